// Round 1
// baseline (576.648 us; speedup 1.0000x reference)
//
#include <hip/hip_runtime.h>
#include <math.h>

// Problem constants (fixed by setup_inputs)
#define OLDN   262144
#define NEWN   65536
#define BATCHN 4
#define NVAL   64
#define BVC    256          // NVAL * BATCHN columns of x_flat
#define R_TILE 32           // segments per block
#define CAP    512          // LDS capacity for a tile's children (avg ~128)
#define UNR    8            // gather loads in flight per thread

__device__ __forceinline__ int lower_bound_i32(const int* __restrict__ a, int n, int key) {
    int lo = 0, hi = n;
    while (lo < hi) {
        int mid = (lo + hi) >> 1;
        if (a[mid] < key) lo = mid + 1; else hi = mid;
    }
    return lo;
}

__global__ __launch_bounds__(256) void maxvalpool_kernel(
    const float* __restrict__ x,     // [B, OLDN, NVAL]
    const float* __restrict__ w,     // [nnz]
    const int*   __restrict__ row,   // [nnz] sorted
    const int*   __restrict__ col,   // [nnz] permutation of OLDN
    float*       __restrict__ out,   // pooled | nnz_ind[0] | nnz_ind[1]
    int nnz)
{
    __shared__ int   s_start[R_TILE + 1];
    __shared__ int   s_col[CAP];
    __shared__ float s_w[CAP];
    __shared__ short s_rr[CAP];
    // winner col index per (c, r) in tile; pad +1 so transpose reads are ~conflict-free
    __shared__ int   s_bestcol[BVC * (R_TILE + 1)];

    const int t  = threadIdx.x;
    const int r0 = blockIdx.x * R_TILE;

    if (t <= R_TILE) s_start[t] = lower_bound_i32(row, nnz, r0 + t);
    __syncthreads();

    const int s0  = s_start[0];
    const int cnt = s_start[R_TILE] - s0;
    const bool use_lds = (cnt <= CAP);
    if (use_lds) {
        for (int i = t; i < cnt; i += 256) {
            s_col[i] = col[s0 + i];
            s_w[i]   = w[s0 + i];
            s_rr[i]  = (short)(row[s0 + i] - r0);
        }
    }
    __syncthreads();

    const int b = t >> 6;        // batch index (wave id)
    const int v = t & 63;        // value index (lane)
    const int c = (v << 2) | b;  // x_flat column = v*B + b
    const float* xb = x + (size_t)b * (OLDN * NVAL) + v;

    if (use_lds) {
        int   cur      = 0;           // row[s0] == r0 (every segment non-empty)
        float best_wv  = -INFINITY;
        float best_val = 0.f;
        int   best_col = 0;
        for (int base = 0; base < cnt; base += UNR) {
            int   ccs[UNR];
            float vals[UNR];
            const int n = cnt - base;
            #pragma unroll
            for (int u = 0; u < UNR; ++u) {
                if (u < n) {
                    ccs[u]  = s_col[base + u];
                    vals[u] = xb[(size_t)ccs[u] * NVAL];   // 8 independent HBM gathers in flight
                }
            }
            #pragma unroll
            for (int u = 0; u < UNR; ++u) {
                if (u < n) {
                    const int rr = s_rr[base + u];
                    if (rr != cur) {   // uniform branch: segment boundary -> flush winner
                        out[((size_t)b * NEWN + (r0 + cur)) * NVAL + v] = best_val;
                        s_bestcol[c * (R_TILE + 1) + cur] = best_col;
                        best_wv = -INFINITY;
                        cur = rr;
                    }
                    const float wv = s_w[base + u] * vals[u];  // exact fp32 mul as reference
                    if (wv > best_wv) {                        // strict > == min-index tie-break
                        best_wv = wv; best_val = vals[u]; best_col = ccs[u];
                    }
                }
            }
        }
        out[((size_t)b * NEWN + (r0 + cur)) * NVAL + v] = best_val;
        s_bestcol[c * (R_TILE + 1) + cur] = best_col;
    } else {
        // Defensive fallback (tile children > CAP) — unreachable for this dataset
        for (int rr = 0; rr < R_TILE; ++rr) {
            const int e0 = s_start[rr], e1 = s_start[rr + 1];
            float best_wv = -INFINITY, best_val = 0.f;
            int best_col = 0;
            for (int i = e0; i < e1; ++i) {
                const int   cc  = col[i];
                const float val = xb[(size_t)cc * NVAL];
                const float wv  = w[i] * val;
                if (wv > best_wv) { best_wv = wv; best_val = val; best_col = cc; }
            }
            out[((size_t)b * NEWN + (r0 + rr)) * NVAL + v] = best_val;
            s_bestcol[c * (R_TILE + 1) + rr] = best_col;
        }
    }
    __syncthreads();

    // Transposed index writes: out2[k, c*NEWN + r]; contiguous 32-element bursts over r
    float* out2  = out  + (size_t)BATCHN * NEWN * NVAL;  // nnz_ind[0]
    float* out2b = out2 + (size_t)BVC * NEWN;            // nnz_ind[1]
    #pragma unroll
    for (int j = 0; j < (BVC * R_TILE) / 256; ++j) {
        const int e  = j * 256 + t;
        const int cc = e >> 5;            // / R_TILE
        const int rr = e & (R_TILE - 1);
        const int bc = s_bestcol[cc * (R_TILE + 1) + rr];
        const size_t o = (size_t)cc * NEWN + (r0 + rr);
        out2[o]  = (float)bc;   // winning old-node index
        out2b[o] = (float)cc;   // column index
    }
}

extern "C" void kernel_launch(void* const* d_in, const int* in_sizes, int n_in,
                              void* d_out, int out_size, void* d_ws, size_t ws_size,
                              hipStream_t stream) {
    const float* x   = (const float*)d_in[0];
    const float* w   = (const float*)d_in[1];
    const int*   row = (const int*)d_in[2];
    const int*   col = (const int*)d_in[3];
    float*       out = (float*)d_out;
    const int nnz = in_sizes[3];  // col size == 262144

    dim3 grid(NEWN / R_TILE);
    dim3 block(256);
    maxvalpool_kernel<<<grid, block, 0, stream>>>(x, w, row, col, out, nnz);
}

// Round 2
// 499.388 us; speedup vs baseline: 1.1547x; 1.1547x over previous
//
#include <hip/hip_runtime.h>
#include <math.h>

// Problem constants (fixed by setup_inputs)
#define OLDN   262144
#define NEWN   65536
#define BATCHN 4
#define NVAL   64
#define BVC    256          // NVAL * BATCHN columns of x_flat
#define R_TILE 16           // segments per block
#define CAP    256          // LDS capacity for a tile's children (avg ~64)
#define UNR    8            // gather loads in flight per thread

// Pass 1: segment starts from sorted row[] — one coalesced sweep, no binsearch.
// Every segment is non-empty by construction, so every starts[] entry gets written.
__global__ __launch_bounds__(256) void seg_starts_kernel(
    const int* __restrict__ row, int* __restrict__ starts, int nnz)
{
    int i = blockIdx.x * 256 + threadIdx.x;
    if (i < nnz) {
        if (i == 0) {
            starts[row[0]] = 0;
            starts[NEWN]   = nnz;
        } else if (row[i] != row[i - 1]) {
            starts[row[i]] = i;
        }
    }
}

__global__ __launch_bounds__(256, 8) void maxvalpool_kernel(
    const float* __restrict__ x,      // [B, OLDN, NVAL]
    const float* __restrict__ w,      // [nnz]
    const int*   __restrict__ row,    // [nnz] sorted (fallback path only)
    const int*   __restrict__ col,    // [nnz] permutation of OLDN
    const int*   __restrict__ starts, // [NEWN+1] from pass 1
    float*       __restrict__ out,    // pooled | nnz_ind[0] | nnz_ind[1]
    int nnz)
{
    __shared__ int   s_start[R_TILE + 1];
    __shared__ int   s_col[CAP];
    __shared__ float s_w[CAP];
    __shared__ short s_rr[CAP];
    // winner col index per (c, r) in tile; +1 pad -> transpose reads are 2-way (free)
    __shared__ int   s_bestcol[BVC * (R_TILE + 1)];

    const int t  = threadIdx.x;
    const int r0 = blockIdx.x * R_TILE;

    if (t <= R_TILE) s_start[t] = starts[r0 + t];
    __syncthreads();

    const int s0  = s_start[0];
    const int cnt = s_start[R_TILE] - s0;
    const bool use_lds = (cnt <= CAP);
    if (use_lds) {
        for (int i = t; i < cnt; i += 256) {
            s_col[i] = col[s0 + i];
            s_w[i]   = w[s0 + i];
            s_rr[i]  = (short)(row[s0 + i] - r0);
        }
    }
    __syncthreads();

    const int b = t >> 6;        // batch index (wave id)
    const int v = t & 63;        // value index (lane) -> 256 B coalesced gathers
    const int c = (v << 2) | b;  // x_flat column = v*B + b
    const float* xb = x + (size_t)b * (OLDN * NVAL) + v;

    if (use_lds) {
        int   cur      = 0;           // starts[] is exact, segment r0 non-empty
        float best_wv  = -INFINITY;
        float best_val = 0.f;
        int   best_col = 0;
        for (int base = 0; base < cnt; base += UNR) {
            int   ccs[UNR];
            float vals[UNR];
            const int n = cnt - base;
            #pragma unroll
            for (int u = 0; u < UNR; ++u) {
                if (u < n) {
                    ccs[u]  = s_col[base + u];
                    vals[u] = xb[(size_t)ccs[u] * NVAL];   // independent HBM gathers in flight
                }
            }
            #pragma unroll
            for (int u = 0; u < UNR; ++u) {
                if (u < n) {
                    const int rr = s_rr[base + u];
                    if (rr != cur) {   // uniform branch: segment boundary -> flush winner
                        out[((size_t)b * NEWN + (r0 + cur)) * NVAL + v] = best_val;
                        s_bestcol[c * (R_TILE + 1) + cur] = best_col;
                        best_wv = -INFINITY;
                        cur = rr;
                    }
                    const float wv = s_w[base + u] * vals[u];  // exact fp32 mul as reference
                    if (wv > best_wv) {                        // strict > == min-index tie-break
                        best_wv = wv; best_val = vals[u]; best_col = ccs[u];
                    }
                }
            }
        }
        out[((size_t)b * NEWN + (r0 + cur)) * NVAL + v] = best_val;
        s_bestcol[c * (R_TILE + 1) + cur] = best_col;
    } else {
        // Defensive fallback (tile children > CAP) — unreachable for this dataset
        for (int rr = 0; rr < R_TILE; ++rr) {
            const int e0 = s_start[rr], e1 = s_start[rr + 1];
            float best_wv = -INFINITY, best_val = 0.f;
            int best_col = 0;
            for (int i = e0; i < e1; ++i) {
                const int   cc  = col[i];
                const float val = xb[(size_t)cc * NVAL];
                const float wv  = w[i] * val;
                if (wv > best_wv) { best_wv = wv; best_val = val; best_col = cc; }
            }
            out[((size_t)b * NEWN + (r0 + rr)) * NVAL + v] = best_val;
            s_bestcol[c * (R_TILE + 1) + rr] = best_col;
        }
    }
    __syncthreads();

    // Transposed index writes: out2[k, c*NEWN + r]; 16-element (64 B) bursts over r;
    // adjacent blocks fill adjacent half-lines concurrently -> combine in L2.
    float* out2  = out  + (size_t)BATCHN * NEWN * NVAL;  // nnz_ind[0]
    float* out2b = out2 + (size_t)BVC * NEWN;            // nnz_ind[1]
    #pragma unroll
    for (int j = 0; j < (BVC * R_TILE) / 256; ++j) {
        const int e  = j * 256 + t;
        const int cc = e >> 4;            // / R_TILE
        const int rr = e & (R_TILE - 1);
        const int bc = s_bestcol[cc * (R_TILE + 1) + rr];
        const size_t o = (size_t)cc * NEWN + (r0 + rr);
        out2[o]  = (float)bc;   // winning old-node index
        out2b[o] = (float)cc;   // column index
    }
}

extern "C" void kernel_launch(void* const* d_in, const int* in_sizes, int n_in,
                              void* d_out, int out_size, void* d_ws, size_t ws_size,
                              hipStream_t stream) {
    const float* x   = (const float*)d_in[0];
    const float* w   = (const float*)d_in[1];
    const int*   row = (const int*)d_in[2];
    const int*   col = (const int*)d_in[3];
    float*       out = (float*)d_out;
    int*         starts = (int*)d_ws;     // NEWN+1 ints
    const int nnz = in_sizes[3];          // 262144

    seg_starts_kernel<<<(nnz + 255) / 256, 256, 0, stream>>>(row, starts, nnz);

    dim3 grid(NEWN / R_TILE);
    dim3 block(256);
    maxvalpool_kernel<<<grid, block, 0, stream>>>(x, w, row, col, starts, out, nnz);
}

// Round 3
// 467.210 us; speedup vs baseline: 1.2342x; 1.0689x over previous
//
#include <hip/hip_runtime.h>
#include <math.h>

// Problem constants (fixed by setup_inputs)
#define OLDN   262144
#define NEWN   65536
#define BATCHN 4
#define NVAL   64
#define BVC    256          // NVAL * BATCHN columns of x_flat
#define R_TILE 16           // segments per block
#define CAP    256          // LDS capacity for a tile's children (avg ~64)
#define UNR    16           // gather loads in flight per thread (branch-free)

// Pass 1: segment starts from sorted row[] — one coalesced sweep, no binsearch.
__global__ __launch_bounds__(256) void seg_starts_kernel(
    const int* __restrict__ row, int* __restrict__ starts, int nnz)
{
    int i = blockIdx.x * 256 + threadIdx.x;
    if (i < nnz) {
        if (i == 0) {
            starts[row[0]] = 0;
            starts[NEWN]   = nnz;
        } else if (row[i] != row[i - 1]) {
            starts[row[i]] = i;
        }
    }
}

__global__ __launch_bounds__(256, 8) void maxvalpool_kernel(
    const float* __restrict__ x,      // [B, OLDN, NVAL]
    const float* __restrict__ w,      // [nnz]
    const int*   __restrict__ row,    // [nnz] sorted (fallback path only)
    const int*   __restrict__ col,    // [nnz] permutation of OLDN
    const int*   __restrict__ starts, // [NEWN+1] from pass 1
    float*       __restrict__ out,    // pooled | nnz_ind[0] | nnz_ind[1]
    int nnz)
{
    __shared__ int   s_start[R_TILE + 1];
    __shared__ int   s_col[CAP + UNR];
    __shared__ float s_w[CAP + UNR];
    __shared__ short s_rr[CAP + UNR];
    // winner col index per (c, r) in tile; +1 pad -> transpose reads conflict-cheap
    __shared__ int   s_bestcol[BVC * (R_TILE + 1)];

    const int t  = threadIdx.x;
    const int r0 = blockIdx.x * R_TILE;

    if (t <= R_TILE) s_start[t] = starts[r0 + t];
    __syncthreads();

    const int s0      = s_start[0];
    const int cnt     = s_start[R_TILE] - s0;
    const int cnt_pad = (cnt + UNR - 1) & ~(UNR - 1);
    const bool use_lds = (cnt <= CAP);
    if (use_lds) {
        for (int i = t; i < cnt_pad; i += 256) {
            if (i < cnt) {
                s_col[i] = col[s0 + i];
                s_w[i]   = w[s0 + i];
                s_rr[i]  = (short)(row[s0 + i] - r0);
            } else {
                // Sentinel: NaN weight -> wv=NaN -> (wv > best) always false, never wins.
                // rr = R_TILE-1 == rr of last real element (last segment non-empty),
                // so no spurious segment flush.
                s_col[i] = 0;
                s_w[i]   = __int_as_float(0x7fc00000);
                s_rr[i]  = (short)(R_TILE - 1);
            }
        }
    }
    __syncthreads();

    const int b = t >> 6;        // batch index (wave id)
    const int v = t & 63;        // value index (lane) -> 256 B coalesced gathers
    const int c = (v << 2) | b;  // x_flat column = v*B + b
    const float* xb = x + (size_t)b * (OLDN * NVAL) + v;

    if (use_lds) {
        int   cur      = 0;           // starts[] is exact, segment r0 non-empty
        float best_wv  = -INFINITY;
        float best_val = 0.f;
        int   best_col = 0;
        for (int base = 0; base < cnt_pad; base += UNR) {
            // Branch-free: UNR independent gathers in flight before any use.
            int ccs[UNR];
            #pragma unroll
            for (int u = 0; u < UNR; ++u) ccs[u] = s_col[base + u];
            float vals[UNR];
            #pragma unroll
            for (int u = 0; u < UNR; ++u) vals[u] = xb[(size_t)ccs[u] * NVAL];
            #pragma unroll
            for (int u = 0; u < UNR; ++u) {
                const int rr = s_rr[base + u];
                if (rr != cur) {   // uniform branch: segment boundary -> flush winner
                    out[((size_t)b * NEWN + (r0 + cur)) * NVAL + v] = best_val;
                    s_bestcol[c * (R_TILE + 1) + cur] = best_col;
                    best_wv = -INFINITY;
                    cur = rr;
                }
                const float wv = s_w[base + u] * vals[u];  // exact fp32 mul as reference
                if (wv > best_wv) {                        // strict > == min-index tie-break
                    best_wv = wv; best_val = vals[u]; best_col = ccs[u];
                }
            }
        }
        out[((size_t)b * NEWN + (r0 + cur)) * NVAL + v] = best_val;
        s_bestcol[c * (R_TILE + 1) + cur] = best_col;
    } else {
        // Defensive fallback (tile children > CAP) — unreachable for this dataset
        for (int rr = 0; rr < R_TILE; ++rr) {
            const int e0 = s_start[rr], e1 = s_start[rr + 1];
            float best_wv = -INFINITY, best_val = 0.f;
            int best_col = 0;
            for (int i = e0; i < e1; ++i) {
                const int   cc  = col[i];
                const float val = xb[(size_t)cc * NVAL];
                const float wv  = w[i] * val;
                if (wv > best_wv) { best_wv = wv; best_val = val; best_col = cc; }
            }
            out[((size_t)b * NEWN + (r0 + rr)) * NVAL + v] = best_val;
            s_bestcol[c * (R_TILE + 1) + rr] = best_col;
        }
    }
    __syncthreads();

    // Transposed index writes: out2[k, c*NEWN + r]; 16-element (64 B) bursts over r;
    // adjacent blocks fill adjacent half-lines concurrently -> combine in L2.
    float* out2  = out  + (size_t)BATCHN * NEWN * NVAL;  // nnz_ind[0]
    float* out2b = out2 + (size_t)BVC * NEWN;            // nnz_ind[1]
    #pragma unroll
    for (int j = 0; j < (BVC * R_TILE) / 256; ++j) {
        const int e  = j * 256 + t;
        const int cc = e >> 4;            // / R_TILE
        const int rr = e & (R_TILE - 1);
        const int bc = s_bestcol[cc * (R_TILE + 1) + rr];
        const size_t o = (size_t)cc * NEWN + (r0 + rr);
        out2[o]  = (float)bc;   // winning old-node index
        out2b[o] = (float)cc;   // column index
    }
}

extern "C" void kernel_launch(void* const* d_in, const int* in_sizes, int n_in,
                              void* d_out, int out_size, void* d_ws, size_t ws_size,
                              hipStream_t stream) {
    const float* x   = (const float*)d_in[0];
    const float* w   = (const float*)d_in[1];
    const int*   row = (const int*)d_in[2];
    const int*   col = (const int*)d_in[3];
    float*       out = (float*)d_out;
    int*         starts = (int*)d_ws;     // NEWN+1 ints
    const int nnz = in_sizes[3];          // 262144

    seg_starts_kernel<<<(nnz + 255) / 256, 256, 0, stream>>>(row, starts, nnz);

    dim3 grid(NEWN / R_TILE);
    dim3 block(256);
    maxvalpool_kernel<<<grid, block, 0, stream>>>(x, w, row, col, starts, out, nnz);
}